// Round 5
// baseline (582.913 us; speedup 1.0000x reference)
//
#include <hip/hip_runtime.h>

// Fused 2-layer LSTM (H=50, D=5, T=512, B=4096) + linear head — v3.
// 512 blocks x 256 threads (4 waves), NB=8 batches/block, 2 blocks/CU with
// INDEPENDENT barriers -> one block's MFMA phase overlaps the other's
// trans-heavy activation phase (anti-phase is the stable attractor under
// pipe contention). Each wave does BOTH layers for its j-range:
//   L0: gates0(t)   = [h0(t-1);x(t)] @ W0^T   (2 s-slots, 8 MFMA)
//   L1: gates1(t-1) = [h0(t-1);h1(t-2)] @ W1^T (4 s-slots, 16 MFMA)
// Single-f16 weights (one MFMA per s-slot; hi/lo dropped — measured absmax
// has sat at the bf16 comparison floor 2^-11 for 3 rounds of headroom).
// M-rows 8..15 unused (NB=8); activation work re-compacted to full wave
// width via __shfl_xor(acc1,32): lanes<32 act L0 cells, lanes>=32 act L1
// cells -> 40 trans instrs/wave/tick (not 80). Cell state in registers.

#define NB 8
#define BLK 256
#define TT 512
#define LOG2E 1.44269504088896340736f
#define SA 72            // _Float16 per A row (K=64 pad, skewed stride)
#define SXR 264          // floats per batch row of x chunk

typedef _Float16 half8 __attribute__((ext_vector_type(8)));
typedef __attribute__((ext_vector_type(4))) float f32x4;

#define MFMAH(a, b, c) __builtin_amdgcn_mfma_f32_16x16x32_f16((a), (b), (c), 0, 0, 0)

__device__ __forceinline__ float fexp2(float x) { return __builtin_amdgcn_exp2f(x); }
__device__ __forceinline__ float frcp(float x)  { return __builtin_amdgcn_rcpf(x); }
__device__ __forceinline__ float sigm(float x)  { return frcp(1.f + fexp2(-LOG2E * x)); }
__device__ __forceinline__ float tanh_(float x) { return 2.f * frcp(1.f + fexp2(-2.f * LOG2E * x)) - 1.f; }

__global__ __launch_bounds__(256, 2) void lstm2_v3(
    const float* __restrict__ x,     // [4096][512][5]
    const float* __restrict__ Wih0,  // [200][5]
    const float* __restrict__ Whh0,  // [200][50]
    const float* __restrict__ bih0,  // [200]
    const float* __restrict__ bhh0,  // [200]
    const float* __restrict__ Wih1,  // [200][50]
    const float* __restrict__ Whh1,  // [200][50]
    const float* __restrict__ bih1,  // [200]
    const float* __restrict__ bhh1,  // [200]
    const float* __restrict__ Wlin,  // [1][50]
    const float* __restrict__ blin,  // [1]
    float* __restrict__ out)         // [4096]
{
    // A buffers, double-buffered. sA0 row: [h0 k=0..49 | x k=50..54 | pad]
    // sA1 row: [h1 k=0..49 | pad]. Rows 8..15 and pads stay zero forever.
    __shared__ __align__(16) _Float16 sA0[2][16 * SA];
    __shared__ __align__(16) _Float16 sA1[2][16 * SA];
    __shared__ __align__(16) float sX[NB * SXR];

    const int tid = threadIdx.x;
    const int w = tid >> 6, l = tid & 63, c = l >> 4, ln = l & 15;
    const int bb0 = blockIdx.x * NB;
    const int j = 16 * w + ln;
    const bool jv = (j < 50);
    const bool low = (l < 32);

    for (int i = tid; i < 2 * 16 * SA; i += BLK) {
        (&sA0[0][0])[i] = (_Float16)0.f;
        (&sA1[0][0])[i] = (_Float16)0.f;
    }

    // ---- single-f16 B-frags in registers for all 512 steps ----
    // k-slot convention (A and B identical): k = 32*s + 8*c + jj.
    half8 b0[4][2], b1[4][4];
    float bias0[4], bias1[4];
#pragma unroll
    for (int p = 0; p < 4; ++p) {
        const int g = p * 50 + j;
#pragma unroll
        for (int s = 0; s < 2; ++s) {
            half8 tb;
#pragma unroll
            for (int jj = 0; jj < 8; ++jj) {
                int k = 32 * s + 8 * c + jj;
                float v = 0.f;
                if (jv) {
                    if (k < 50)      v = Whh0[g * 50 + k];
                    else if (k < 55) v = Wih0[g * 5 + (k - 50)];
                }
                tb[jj] = (_Float16)v;
            }
            b0[p][s] = tb;
        }
#pragma unroll
        for (int s = 0; s < 4; ++s) {
            half8 tb;
#pragma unroll
            for (int jj = 0; jj < 8; ++jj) {
                int k = 32 * s + 8 * c + jj;
                float v = 0.f;
                if (jv) {
                    if (k < 50)                   v = Wih1[g * 50 + k];
                    else if (k >= 64 && k < 114)  v = Whh1[g * 50 + (k - 64)];
                }
                tb[jj] = (_Float16)v;
            }
            b1[p][s] = tb;
        }
        bias0[p] = jv ? (bih0[g] + bhh0[g]) : 0.f;
        bias1[p] = jv ? (bih1[g] + bhh1[g]) : 0.f;
    }

    // cell state: lanes<32 hold c0 of (batch=4*(c&1)+r, j); lanes>=32 hold c1.
    float cst[4] = {0.f, 0.f, 0.f, 0.f};

    // ---- x chunk 0 (times 0..31) -> sX; prefetch chunk 1 (32..63) ----
    float xr[5];
#pragma unroll
    for (int q = 0; q < 5; ++q) {
        int e = tid + q * BLK, b = e / 160, r = e - b * 160;
        xr[q] = x[(size_t)(bb0 + b) * 2560 + r];
    }
#pragma unroll
    for (int q = 0; q < 5; ++q) {
        int e = tid + q * BLK, b = e / 160, r = e - b * 160;
        int ts = r / 5, d = r - ts * 5;
        sX[b * SXR + ts * 8 + d] = xr[q];
    }
#pragma unroll
    for (int q = 0; q < 5; ++q) {
        int e = tid + q * BLK, b = e / 160, r = e - b * 160;
        xr[q] = x[(size_t)(bb0 + b) * 2560 + 160 + r];
    }
    __syncthreads();   // zero-init + sX visible

    if (tid < NB * 5) {    // x(0) -> buf[1] (tick 0 reads rb=1)
        int b = tid / 5, d = tid - 5 * b;
        sA0[1][b * SA + 50 + d] = (_Float16)x[(size_t)(bb0 + b) * 2560 + d];
    }
    __syncthreads();

    for (int t = 0; t <= TT; ++t) {
        const int rb = (t + 1) & 1;
        const int wb = t & 1;

        if ((t & 31) == 31 && t < TT - 1) {
#pragma unroll
            for (int q = 0; q < 5; ++q) {
                int e = tid + q * BLK, b = e / 160, r = e - b * 160;
                int ts = r / 5, d = r - ts * 5;
                sX[b * SXR + ts * 8 + d] = xr[q];
            }
            if (t + 33 < TT) {
#pragma unroll
                for (int q = 0; q < 5; ++q) {
                    int e = tid + q * BLK, b = e / 160, r = e - b * 160;
                    xr[q] = x[(size_t)(bb0 + b) * 2560 + (size_t)(t + 33) * 5 + r];
                }
            }
            __syncthreads();
        }

        // x(t+1) -> buf[wb] x-slots (read next tick; overlaps MFMA below)
        if (t < TT - 1 && tid < NB * 5) {
            int b = tid / 5, d = tid - 5 * b, tl1 = (t + 1) & 31;
            sA0[wb][b * SA + 50 + d] = (_Float16)sX[b * SXR + tl1 * 8 + d];
        }

        const bool doL0 = (t < TT), doL1 = (t > 0);

        // ---- A-frag reads (L1 s=0,1 reuses the sA0 reads of L0) ----
        half8 a01_0 = *(const half8*)&sA0[rb][ln * SA + 0  + 8 * c];
        half8 a01_1 = *(const half8*)&sA0[rb][ln * SA + 32 + 8 * c];
        half8 a23_0 = *(const half8*)&sA1[rb][ln * SA + 0  + 8 * c];
        half8 a23_1 = *(const half8*)&sA1[rb][ln * SA + 32 + 8 * c];

        f32x4 acc0[4], acc1[4];
#pragma unroll
        for (int p = 0; p < 4; ++p) {
            f32x4 a0; a0[0] = bias0[p]; a0[1] = bias0[p]; a0[2] = bias0[p]; a0[3] = bias0[p];
            f32x4 a1; a1[0] = bias1[p]; a1[1] = bias1[p]; a1[2] = bias1[p]; a1[3] = bias1[p];
            acc0[p] = a0; acc1[p] = a1;
        }
        if (doL0) {
#pragma unroll
            for (int p = 0; p < 4; ++p) {
                acc0[p] = MFMAH(a01_0, b0[p][0], acc0[p]);
                acc0[p] = MFMAH(a01_1, b0[p][1], acc0[p]);
            }
        }
        if (doL1) {
#pragma unroll
            for (int p = 0; p < 4; ++p) {
                acc1[p] = MFMAH(a01_0, b1[p][0], acc1[p]);
                acc1[p] = MFMAH(a01_1, b1[p][1], acc1[p]);
                acc1[p] = MFMAH(a23_0, b1[p][2], acc1[p]);
                acc1[p] = MFMAH(a23_1, b1[p][3], acc1[p]);
            }
        }

        // ---- compacted activations: lanes<32 = L0 cells, lanes>=32 = L1 ----
        const bool alive = (low ? doL0 : doL1) && jv;
        _Float16* const dst = low ? &sA0[wb][0] : &sA1[wb][0];
#pragma unroll
        for (int r = 0; r < 4; ++r) {
            float comb[4];
#pragma unroll
            for (int p = 0; p < 4; ++p) {
                float sw = __shfl_xor(acc1[p][r], 32, 64);
                comb[p] = low ? acc0[p][r] : sw;
            }
            float gi = sigm(comb[0]);
            float gf = sigm(comb[1]);
            float gg = tanh_(comb[2]);
            float go = sigm(comb[3]);
            float nc = gf * cst[r] + gi * gg;
            if (alive) {
                cst[r] = nc;
                float h = go * tanh_(nc);
                dst[(4 * (c & 1) + r) * SA + j] = (_Float16)h;
            }
        }
        __syncthreads();
    }

    // ---- linear head on final h1(511) (tick 512 wrote buf[0]) ----
    if (tid < NB) {
        float s = blin[0];
#pragma unroll
        for (int jj = 0; jj < 50; ++jj)
            s += Wlin[jj] * (float)sA1[0][tid * SA + jj];
        out[bb0 + tid] = s;
    }
}

extern "C" void kernel_launch(void* const* d_in, const int* in_sizes, int n_in,
                              void* d_out, int out_size, void* d_ws, size_t ws_size,
                              hipStream_t stream) {
    (void)in_sizes; (void)n_in; (void)d_ws; (void)ws_size; (void)out_size;
    const float* x    = (const float*)d_in[0];
    const float* Wih0 = (const float*)d_in[1];
    const float* Whh0 = (const float*)d_in[2];
    const float* bih0 = (const float*)d_in[3];
    const float* bhh0 = (const float*)d_in[4];
    const float* Wih1 = (const float*)d_in[5];
    const float* Whh1 = (const float*)d_in[6];
    const float* bih1 = (const float*)d_in[7];
    const float* bhh1 = (const float*)d_in[8];
    const float* Wlin = (const float*)d_in[9];
    const float* blin = (const float*)d_in[10];

    lstm2_v3<<<dim3(512), dim3(256), 0, stream>>>(
        x, Wih0, Whh0, bih0, bhh0, Wih1, Whh1, bih1, bhh1, Wlin, blin,
        (float*)d_out);
}

// Round 6
// 420.934 us; speedup vs baseline: 1.3848x; 1.3848x over previous
//
#include <hip/hip_runtime.h>

// Fused 2-layer LSTM (H=50, D=5, T=512, B=4096) + linear head — v4.
// = R4 structure (best measured) + single-f16 weights + pre-scaled gates.
// grid=256 (1 block/CU), block=512 (8 waves), NB=16 batches/block.
// Waves 0-3: layer-0 step t; waves 4-7: layer-1 step t-1; ONE barrier/tick.
// Weights/biases pre-scaled by -log2e (i,f,o) / -2log2e (g) so activations
// are rcp(1+exp2(acc)) with no input multiply. Single f16 weights: R5
// measured absmax 4.88e-4 == pure-fp32 R1 -> lo-MFMAs were pure waste.
// L0: gates0(t) = [h0(t-1);x(t)] @ W0^T   (2 s-slots, 8 MFMA/wave)
// L1: gates1(t-1) = [h0(t-1);h1(t-2)] @ W1^T (4 s-slots, 16 MFMA/wave)

#define NB 16
#define BLK 512
#define TT 512
#define LOG2E 1.44269504088896340736f
#define SA 72            // _Float16 per A row (K=64 pad, skewed stride)
#define SXR 264          // floats per batch row of x chunk

typedef _Float16 half8 __attribute__((ext_vector_type(8)));
typedef __attribute__((ext_vector_type(4))) float f32x4;

#define MFMAH(a, b, c) __builtin_amdgcn_mfma_f32_16x16x32_f16((a), (b), (c), 0, 0, 0)

__device__ __forceinline__ float fexp2(float x) { return __builtin_amdgcn_exp2f(x); }
__device__ __forceinline__ float frcp(float x)  { return __builtin_amdgcn_rcpf(x); }
// pre-scaled forms: acc already = -log2e*pre (sigmoid) or -2log2e*pre (tanh)
__device__ __forceinline__ float sigm_s(float a)  { return frcp(1.f + fexp2(a)); }
__device__ __forceinline__ float tanh_s(float a)  { return 2.f * frcp(1.f + fexp2(a)) - 1.f; }
__device__ __forceinline__ float tanh_(float x)   { return tanh_s(-2.f * LOG2E * x); }

__global__ __launch_bounds__(512, 2) void lstm2_v4(
    const float* __restrict__ x,     // [4096][512][5]
    const float* __restrict__ Wih0,  // [200][5]
    const float* __restrict__ Whh0,  // [200][50]
    const float* __restrict__ bih0,  // [200]
    const float* __restrict__ bhh0,  // [200]
    const float* __restrict__ Wih1,  // [200][50]
    const float* __restrict__ Whh1,  // [200][50]
    const float* __restrict__ bih1,  // [200]
    const float* __restrict__ bhh1,  // [200]
    const float* __restrict__ Wlin,  // [1][50]
    const float* __restrict__ blin,  // [1]
    float* __restrict__ out)         // [4096]
{
    // A buffers, double-buffered. sA0 row: [h0 k=0..49 | x k=50..54 | pad]
    // sA1 row: [h1 k=0..49 | pad]. Pads zeroed once, never rewritten.
    __shared__ __align__(16) _Float16 sA0[2][16 * SA];
    __shared__ __align__(16) _Float16 sA1[2][16 * SA];
    __shared__ __align__(16) float sX[16 * SXR];

    const int tid = threadIdx.x;
    const int w = tid >> 6, l = tid & 63, c = l >> 4, ln = l & 15;
    const int grp = w >> 2, wl = w & 3;
    const int bb0 = blockIdx.x * NB;
    const int j = 16 * wl + ln;
    const bool jv = (j < 50);

    for (int i = tid; i < 2 * 16 * SA; i += BLK) {
        (&sA0[0][0])[i] = (_Float16)0.f;
        (&sA1[0][0])[i] = (_Float16)0.f;
    }

    // ---- single-f16 B-frags (pre-scaled) in registers for all 512 steps ----
    // k-slot convention (A and B identical): k = 32*s + 8*c + jj.
    // gate scale: p=0(i),1(f),3(o): -log2e ; p=2(g): -2log2e.
    half8 bfr[4][4];
    float bias[4];
#pragma unroll
    for (int p = 0; p < 4; ++p) {
        const float gs = (p == 2) ? (-2.f * LOG2E) : (-LOG2E);
        const int g = p * 50 + j;
#pragma unroll
        for (int s = 0; s < 4; ++s) {
            half8 tb;
#pragma unroll
            for (int jj = 0; jj < 8; ++jj) {
                int k = 32 * s + 8 * c + jj;
                float v = 0.f;
                if (jv) {
                    if (grp == 0) {
                        if (k < 50)      v = Whh0[g * 50 + k];
                        else if (k < 55) v = Wih0[g * 5 + (k - 50)];
                    } else {
                        if (k < 50)                  v = Wih1[g * 50 + k];
                        else if (k >= 64 && k < 114) v = Whh1[g * 50 + (k - 64)];
                    }
                }
                tb[jj] = (_Float16)(v * gs);
            }
            bfr[p][s] = tb;
        }
        float bv = jv ? ((grp == 0) ? (bih0[g] + bhh0[g]) : (bih1[g] + bhh1[g])) : 0.f;
        bias[p] = bv * gs;
    }

    float cst[4] = {0.f, 0.f, 0.f, 0.f};   // cell state: batches 4c+r, own j

    // ---- x chunk 0 -> sX; prefetch chunk 1 ----
    float xr[5];
#pragma unroll
    for (int q = 0; q < 5; ++q) {
        int e = tid + q * BLK, b = e / 160, r = e - b * 160;
        xr[q] = x[(size_t)(bb0 + b) * 2560 + r];
    }
#pragma unroll
    for (int q = 0; q < 5; ++q) {
        int e = tid + q * BLK, b = e / 160, r = e - b * 160;
        int ts = r / 5, d = r - ts * 5;
        sX[b * SXR + ts * 8 + d] = xr[q];
    }
#pragma unroll
    for (int q = 0; q < 5; ++q) {
        int e = tid + q * BLK, b = e / 160, r = e - b * 160;
        xr[q] = x[(size_t)(bb0 + b) * 2560 + 160 + r];
    }
    __syncthreads();   // zero-init + sX visible

    if (tid < 80) {    // x(0) -> buf[1] (tick 0 reads rb=1)
        int b = tid / 5, d = tid - 5 * b;
        sA0[1][b * SA + 50 + d] = (_Float16)x[(size_t)(bb0 + b) * 2560 + d];
    }
    __syncthreads();

    for (int t = 0; t <= TT; ++t) {
        const int rb = (t + 1) & 1;
        const int wb = t & 1;

        if ((t & 31) == 31 && t < TT - 1) {
#pragma unroll
            for (int q = 0; q < 5; ++q) {
                int e = tid + q * BLK, b = e / 160, r = e - b * 160;
                int ts = r / 5, d = r - ts * 5;
                sX[b * SXR + ts * 8 + d] = xr[q];
            }
            if (t + 33 < TT) {
#pragma unroll
                for (int q = 0; q < 5; ++q) {
                    int e = tid + q * BLK, b = e / 160, r = e - b * 160;
                    xr[q] = x[(size_t)(bb0 + b) * 2560 + (size_t)(t + 33) * 5 + r];
                }
            }
            __syncthreads();
        }

        // x(t+1) -> buf[wb] x-slots (read next tick; overlaps MFMA below)
        if (t < TT - 1 && tid < 80) {
            int b = tid / 5, d = tid - 5 * b, tl1 = (t + 1) & 31;
            sA0[wb][b * SA + 50 + d] = (_Float16)sX[b * SXR + tl1 * 8 + d];
        }

        if (grp == 0) {
            // ======== layer-0, step t ========
            if (t < TT) {
                f32x4 acc[4];
#pragma unroll
                for (int p = 0; p < 4; ++p) {
                    f32x4 a; a[0] = bias[p]; a[1] = bias[p]; a[2] = bias[p]; a[3] = bias[p];
                    acc[p] = a;
                }
#pragma unroll
                for (int s = 0; s < 2; ++s) {
                    half8 a = *(const half8*)&sA0[rb][ln * SA + 32 * s + 8 * c];
#pragma unroll
                    for (int p = 0; p < 4; ++p)
                        acc[p] = MFMAH(a, bfr[p][s], acc[p]);
                }
                if (jv) {
#pragma unroll
                    for (int r = 0; r < 4; ++r) {
                        float gi = sigm_s(acc[0][r]);
                        float gf = sigm_s(acc[1][r]);
                        float gg = tanh_s(acc[2][r]);
                        float go = sigm_s(acc[3][r]);
                        cst[r] = gf * cst[r] + gi * gg;
                        float h = go * tanh_(cst[r]);
                        sA0[wb][(4 * c + r) * SA + j] = (_Float16)h;
                    }
                }
            }
        } else {
            // ======== layer-1, step t-1 ========
            if (t > 0) {
                f32x4 acc[4];
#pragma unroll
                for (int p = 0; p < 4; ++p) {
                    f32x4 a; a[0] = bias[p]; a[1] = bias[p]; a[2] = bias[p]; a[3] = bias[p];
                    acc[p] = a;
                }
#pragma unroll
                for (int s = 0; s < 4; ++s) {
                    half8 a = (s < 2)
                        ? *(const half8*)&sA0[rb][ln * SA + 32 * s + 8 * c]
                        : *(const half8*)&sA1[rb][ln * SA + 32 * (s - 2) + 8 * c];
#pragma unroll
                    for (int p = 0; p < 4; ++p)
                        acc[p] = MFMAH(a, bfr[p][s], acc[p]);
                }
                if (jv) {
#pragma unroll
                    for (int r = 0; r < 4; ++r) {
                        float gi = sigm_s(acc[0][r]);
                        float gf = sigm_s(acc[1][r]);
                        float gg = tanh_s(acc[2][r]);
                        float go = sigm_s(acc[3][r]);
                        cst[r] = gf * cst[r] + gi * gg;
                        float h = go * tanh_(cst[r]);
                        sA1[wb][(4 * c + r) * SA + j] = (_Float16)h;
                    }
                }
            }
        }
        __syncthreads();
    }

    // ---- linear head on final h1(511) (tick 512 wrote buf[0]) ----
    if (tid < NB) {
        float s = blin[0];
#pragma unroll
        for (int jj = 0; jj < 50; ++jj)
            s += Wlin[jj] * (float)sA1[0][tid * SA + jj];
        out[bb0 + tid] = s;
    }
}

extern "C" void kernel_launch(void* const* d_in, const int* in_sizes, int n_in,
                              void* d_out, int out_size, void* d_ws, size_t ws_size,
                              hipStream_t stream) {
    (void)in_sizes; (void)n_in; (void)d_ws; (void)ws_size; (void)out_size;
    const float* x    = (const float*)d_in[0];
    const float* Wih0 = (const float*)d_in[1];
    const float* Whh0 = (const float*)d_in[2];
    const float* bih0 = (const float*)d_in[3];
    const float* bhh0 = (const float*)d_in[4];
    const float* Wih1 = (const float*)d_in[5];
    const float* Whh1 = (const float*)d_in[6];
    const float* bih1 = (const float*)d_in[7];
    const float* bhh1 = (const float*)d_in[8];
    const float* Wlin = (const float*)d_in[9];
    const float* blin = (const float*)d_in[10];

    lstm2_v4<<<dim3(256), dim3(512), 0, stream>>>(
        x, Wih0, Whh0, bih0, bhh0, Wih1, Whh1, bih1, bhh1, Wlin, blin,
        (float*)d_out);
}

// Round 7
// 372.067 us; speedup vs baseline: 1.5667x; 1.1313x over previous
//
#include <hip/hip_runtime.h>

// Fused 2-layer LSTM (H=50, D=5, T=512, B=4096) + linear head — v5.
// = R6/v4 dataflow (best: 421 us) + issue-slot cuts under the additive-issue
// model (per-SIMD MFMA issue + VALU issue add; measured MfmaUtil+VALUBusy~80%).
//   1) 7-trans cell update (common denominator):
//      c' = [c(1+u)(1+v) + (1-v)(1+w)] / [(1+w)(1+u)(1+v)],
//      h  = (1-z)/((1+y)(1+z)),  u,v,w,y = exp2(pre-scaled accs), z from c'.
//      zarg clamped at 80 so the saturated-tanh path stays finite (h -> -o).
//   2) bias rides in as the MFMA C operand (no 16x acc-init movs per tick).
//   3) 2x tick unroll: rb/wb compile-time, staging check only in odd ticks.
//   4) s_setprio(1) around MFMA clusters (role-diverse waves, T5).
// grid=256 (1 block/CU), block=512 (8 waves), NB=16 batches/block.
// Waves 0-3: layer-0 step t; waves 4-7: layer-1 step t-1; ONE barrier/tick.

#define NB 16
#define BLK 512
#define TT 512
#define LOG2E 1.44269504088896340736f
#define SA 72            // _Float16 per A row (K=64 pad, skewed stride)
#define SXR 264          // floats per batch row of x chunk

typedef _Float16 half8 __attribute__((ext_vector_type(8)));
typedef __attribute__((ext_vector_type(4))) float f32x4;

#define MFMAH(a, b, c) __builtin_amdgcn_mfma_f32_16x16x32_f16((a), (b), (c), 0, 0, 0)

__device__ __forceinline__ float fexp2(float x) { return __builtin_amdgcn_exp2f(x); }
__device__ __forceinline__ float frcp(float x)  { return __builtin_amdgcn_rcpf(x); }

// ---- 7-trans activation + cell + h-write for 4 batch rows ----
#define CELL_UPDATE(ACCX, BUF, WBX)                                         \
    _Pragma("unroll")                                                       \
    for (int r = 0; r < 4; ++r) {                                           \
        float eu = fexp2(ACCX[0][r]);   /* i: u = e^{-ai} */                \
        float ew = fexp2(ACCX[1][r]);   /* f */                             \
        float ev = fexp2(ACCX[2][r]);   /* g (2x scale) */                  \
        float ey = fexp2(ACCX[3][r]);   /* o */                             \
        float pu = 1.f + eu, pw = 1.f + ew, pv = 1.f + ev;                  \
        float P  = pu * pv;                                                 \
        float rD = frcp(P * pw);                                            \
        float N  = cst[r] * P + (2.f - pv) * pw;                            \
        float cn = N * rD;                                                  \
        cst[r] = cn;                                                        \
        float za = fminf(cn * (-2.f * LOG2E), 80.f);                        \
        float ez = fexp2(za);                                               \
        float pz = 1.f + ez, py = 1.f + ey;                                 \
        float rQ = frcp(py * pz);                                           \
        float h  = (2.f - pz) * rQ;                                         \
        BUF[WBX][(4 * c + r) * SA + j] = (_Float16)h;                       \
    }

// ---- one pipeline tick; RB/WB are literal 0/1 ----
#define TICK(T, RB, WB)                                                     \
    {                                                                       \
        if ((T) < TT - 1 && tid < 80) {                                     \
            int b_ = tid / 5, d_ = tid - 5 * b_, tl1 = ((T) + 1) & 31;      \
            sA0[WB][b_ * SA + 50 + d_] =                                    \
                (_Float16)sX[b_ * SXR + tl1 * 8 + d_];                      \
        }                                                                   \
        if (grp == 0) {                                                     \
            if ((T) < TT) {                                                 \
                __builtin_amdgcn_s_setprio(1);                              \
                half8 a0 = *(const half8*)&sA0[RB][ln * SA + 0 + 8 * c];    \
                half8 a1 = *(const half8*)&sA0[RB][ln * SA + 32 + 8 * c];   \
                f32x4 acc[4];                                               \
                _Pragma("unroll")                                           \
                for (int p = 0; p < 4; ++p) {                               \
                    acc[p] = MFMAH(a0, bfr[p][0], bias4[p]);                \
                    acc[p] = MFMAH(a1, bfr[p][1], acc[p]);                  \
                }                                                           \
                __builtin_amdgcn_s_setprio(0);                              \
                if (jv) { CELL_UPDATE(acc, sA0, WB) }                       \
            }                                                               \
        } else {                                                            \
            if ((T) > 0) {                                                  \
                __builtin_amdgcn_s_setprio(1);                              \
                half8 a0 = *(const half8*)&sA0[RB][ln * SA + 0 + 8 * c];    \
                half8 a1 = *(const half8*)&sA0[RB][ln * SA + 32 + 8 * c];   \
                half8 a2 = *(const half8*)&sA1[RB][ln * SA + 0 + 8 * c];    \
                half8 a3 = *(const half8*)&sA1[RB][ln * SA + 32 + 8 * c];   \
                f32x4 acc[4];                                               \
                _Pragma("unroll")                                           \
                for (int p = 0; p < 4; ++p) {                               \
                    acc[p] = MFMAH(a0, bfr[p][0], bias4[p]);                \
                    acc[p] = MFMAH(a1, bfr[p][1], acc[p]);                  \
                    acc[p] = MFMAH(a2, bfr[p][2], acc[p]);                  \
                    acc[p] = MFMAH(a3, bfr[p][3], acc[p]);                  \
                }                                                           \
                __builtin_amdgcn_s_setprio(0);                              \
                if (jv) { CELL_UPDATE(acc, sA1, WB) }                       \
            }                                                               \
        }                                                                   \
        __syncthreads();                                                    \
    }

// ---- x chunk roll (call sites guarantee (T)&31 == 31) ----
#define STAGE(T)                                                            \
    if ((T) < TT - 1) {                                                     \
        _Pragma("unroll")                                                   \
        for (int q = 0; q < 5; ++q) {                                       \
            int e = tid + q * BLK, b_ = e / 160, r_ = e - b_ * 160;         \
            int ts = r_ / 5, d_ = r_ - ts * 5;                              \
            sX[b_ * SXR + ts * 8 + d_] = xr[q];                             \
        }                                                                   \
        if ((T) + 33 < TT) {                                                \
            _Pragma("unroll")                                               \
            for (int q = 0; q < 5; ++q) {                                   \
                int e = tid + q * BLK, b_ = e / 160, r_ = e - b_ * 160;     \
                xr[q] = x[(size_t)(bb0 + b_) * 2560 +                       \
                          (size_t)((T) + 33) * 5 + r_];                     \
            }                                                               \
        }                                                                   \
        __syncthreads();                                                    \
    }

__global__ __launch_bounds__(512, 2) void lstm2_v5(
    const float* __restrict__ x,     // [4096][512][5]
    const float* __restrict__ Wih0,  // [200][5]
    const float* __restrict__ Whh0,  // [200][50]
    const float* __restrict__ bih0,  // [200]
    const float* __restrict__ bhh0,  // [200]
    const float* __restrict__ Wih1,  // [200][50]
    const float* __restrict__ Whh1,  // [200][50]
    const float* __restrict__ bih1,  // [200]
    const float* __restrict__ bhh1,  // [200]
    const float* __restrict__ Wlin,  // [1][50]
    const float* __restrict__ blin,  // [1]
    float* __restrict__ out)         // [4096]
{
    // A buffers, double-buffered. sA0 row: [h0 k=0..49 | x k=50..54 | pad]
    // sA1 row: [h1 k=0..49 | pad]. Pads zeroed once, never rewritten.
    __shared__ __align__(16) _Float16 sA0[2][16 * SA];
    __shared__ __align__(16) _Float16 sA1[2][16 * SA];
    __shared__ __align__(16) float sX[16 * SXR];

    const int tid = threadIdx.x;
    const int w = tid >> 6, l = tid & 63, c = l >> 4, ln = l & 15;
    const int grp = w >> 2, wl = w & 3;
    const int bb0 = blockIdx.x * NB;
    const int j = 16 * wl + ln;
    const bool jv = (j < 50);

    for (int i = tid; i < 2 * 16 * SA; i += BLK) {
        (&sA0[0][0])[i] = (_Float16)0.f;
        (&sA1[0][0])[i] = (_Float16)0.f;
    }

    // ---- single-f16 B-frags (pre-scaled) + bias-as-C, for all 512 steps ----
    // k-slot convention (A and B identical): k = 32*s + 8*c + jj.
    // gate scale: p=0(i),1(f),3(o): -log2e ; p=2(g): -2log2e.
    half8 bfr[4][4];
    f32x4 bias4[4];
#pragma unroll
    for (int p = 0; p < 4; ++p) {
        const float gs = (p == 2) ? (-2.f * LOG2E) : (-LOG2E);
        const int g = p * 50 + j;
#pragma unroll
        for (int s = 0; s < 4; ++s) {
            half8 tb;
#pragma unroll
            for (int jj = 0; jj < 8; ++jj) {
                int k = 32 * s + 8 * c + jj;
                float v = 0.f;
                if (jv) {
                    if (grp == 0) {
                        if (k < 50)      v = Whh0[g * 50 + k];
                        else if (k < 55) v = Wih0[g * 5 + (k - 50)];
                    } else {
                        if (k < 50)                  v = Wih1[g * 50 + k];
                        else if (k >= 64 && k < 114) v = Whh1[g * 50 + (k - 64)];
                    }
                }
                tb[jj] = (_Float16)(v * gs);
            }
            bfr[p][s] = tb;
        }
        float bv = jv ? ((grp == 0) ? (bih0[g] + bhh0[g]) : (bih1[g] + bhh1[g])) : 0.f;
        bv *= gs;
        f32x4 b4; b4[0] = bv; b4[1] = bv; b4[2] = bv; b4[3] = bv;
        bias4[p] = b4;
    }

    float cst[4] = {0.f, 0.f, 0.f, 0.f};   // cell state: batches 4c+r, own j

    // ---- x chunk 0 -> sX; prefetch chunk 1 into xr ----
    float xr[5];
#pragma unroll
    for (int q = 0; q < 5; ++q) {
        int e = tid + q * BLK, b = e / 160, r = e - b * 160;
        xr[q] = x[(size_t)(bb0 + b) * 2560 + r];
    }
#pragma unroll
    for (int q = 0; q < 5; ++q) {
        int e = tid + q * BLK, b = e / 160, r = e - b * 160;
        int ts = r / 5, d = r - ts * 5;
        sX[b * SXR + ts * 8 + d] = xr[q];
    }
#pragma unroll
    for (int q = 0; q < 5; ++q) {
        int e = tid + q * BLK, b = e / 160, r = e - b * 160;
        xr[q] = x[(size_t)(bb0 + b) * 2560 + 160 + r];
    }
    __syncthreads();   // zero-init + sX visible

    if (tid < 80) {    // x(0) -> buf[1] (tick 0 reads rb=1)
        int b = tid / 5, d = tid - 5 * b;
        sA0[1][b * SA + 50 + d] = (_Float16)x[(size_t)(bb0 + b) * 2560 + d];
    }
    __syncthreads();

    // ---- main loop, 2x unrolled (compile-time rb/wb) ----
    for (int t = 0; t < TT; t += 2) {
        TICK(t, 1, 0)
        if ((t & 31) == 30) { STAGE(t + 1) }   // (t+1)&31 == 31
        TICK(t + 1, 0, 1)
    }
    TICK(TT, 1, 0)

    // ---- linear head on final h1(511) (tick 512 wrote buf[0]) ----
    if (tid < NB) {
        float s = blin[0];
#pragma unroll
        for (int jj = 0; jj < 50; ++jj)
            s += Wlin[jj] * (float)sA1[0][tid * SA + jj];
        out[bb0 + tid] = s;
    }
}

extern "C" void kernel_launch(void* const* d_in, const int* in_sizes, int n_in,
                              void* d_out, int out_size, void* d_ws, size_t ws_size,
                              hipStream_t stream) {
    (void)in_sizes; (void)n_in; (void)d_ws; (void)ws_size; (void)out_size;
    const float* x    = (const float*)d_in[0];
    const float* Wih0 = (const float*)d_in[1];
    const float* Whh0 = (const float*)d_in[2];
    const float* bih0 = (const float*)d_in[3];
    const float* bhh0 = (const float*)d_in[4];
    const float* Wih1 = (const float*)d_in[5];
    const float* Whh1 = (const float*)d_in[6];
    const float* bih1 = (const float*)d_in[7];
    const float* bhh1 = (const float*)d_in[8];
    const float* Wlin = (const float*)d_in[9];
    const float* blin = (const float*)d_in[10];

    lstm2_v5<<<dim3(256), dim3(512), 0, stream>>>(
        x, Wih0, Whh0, bih0, bhh0, Wih1, Whh1, bih1, bhh1, Wlin, blin,
        (float*)d_out);
}